// Round 12
// baseline (264.891 us; speedup 1.0000x reference)
//
#include <hip/hip_runtime.h>
#include <hip/hip_bf16.h>

// Problem dims (fixed by reference)
static constexpr int B_  = 16;
static constexpr int SN_ = 64;
static constexpr int C_  = 480;
static constexpr int T_  = 2;
static constexpr int FY_ = 60;
static constexpr int FX_ = 80;
static constexpr int OS_ = 8;
static constexpr int DIN = 30720;            // C*OS*OS
static constexpr int M_  = 1024;             // B*SN
static constexpr int N1_ = 1024;
static constexpr int N2_ = 256;
static constexpr int K_  = 64;               // clusters
static constexpr int SPLITK = 16;
static constexpr int NCH_ZZ = (DIN / 64) / SPLITK;  // 30 chunks per split
static constexpr int NCH_FW = N1_ / 64;             // 16 chunks
static constexpr int IMG = FY_ * FX_;            // 4800
// prep1 block ranges (256 thr)
static constexpr int NB_W1T = (DIN / 64) * (N1_ / 64);  // 7680
static constexpr int NB_W2P = N2_;                      // 256
// mega2 block ranges (512 thr)
static constexpr int NB_FW   = 480;              // fusew tiles (8 x 60 remap)
static constexpr int CPB2    = 4;                // roi channels per block
static constexpr int NB_ROI2 = 16 * (C_ / CPB2); // 1920

typedef __bf16 bf16x8 __attribute__((ext_vector_type(8)));
typedef float  f32x4  __attribute__((ext_vector_type(4)));
typedef unsigned int u32_as1 __attribute__((address_space(1)));
typedef unsigned int u32_as3 __attribute__((address_space(3)));

__device__ __forceinline__ float bf2f(unsigned short u) {
    union { unsigned int i; float f; } v; v.i = ((unsigned int)u) << 16; return v.f;
}
// RNE f32 -> bf16 bits (inputs finite here)
__device__ __forceinline__ unsigned short f2bf(float f) {
    unsigned int u = __float_as_uint(f);
    u = u + 0x7FFFu + ((u >> 16) & 1u);
    return (unsigned short)(u >> 16);
}
__device__ __forceinline__ void gll16(const void* g, void* l) {
    __builtin_amdgcn_global_load_lds((const u32_as1*)g, (u32_as3*)l, 16, 0, 0);
}

// ---------------------------------------------------------------------------
// MFMA GEMM core v5 (round-11 verbatim) — 4-stage/3-product chunking +
// depth-2 counted vmcnt. Per K-chunk: stage {Ahi, Alo, Bhi, Blo} once
// (8 gll16/thread), compute Ahi.Bhi + Ahi.Blo + Alo.Bhi.
// 512 threads = 8 waves (2m x 4n), tile 128x128, wave-tile 64x32.
// LDS = 2 x 4 x [128][64] bf16 = 128 KB, XOR-swizzled k-slots.
// vmcnt(8) waits current buffer only; WAR guarded by lgkm(0)+SB+barrier.
// ---------------------------------------------------------------------------
template<int NCHUNK, int SEG>
__device__ __forceinline__ void gemm_core(
    const unsigned short* __restrict__ Abase, long long Astride,
    const unsigned short* __restrict__ Bbase, long long Bstride,
    int k0, f32x4 (&acc)[4][2], unsigned short* L)   // L: 2*4*128*64 elems
{
    const int t = threadIdx.x;
    const int w = t >> 6, lane = t & 63;
    const int rl8 = lane >> 3, slot = lane & 7;
    const int wm = w >> 2, wn = w & 3;
    const int fr = lane & 15, fg = lane >> 4;
    const int swz8 = (slot ^ rl8) * 8;       // row&7 == rl8 for staging rows

    long long arow[2], brow[2];
    int ci[2];
#pragma unroll
    for (int c = 0; c < 2; ++c) {
        ci[c] = w * 2 + c;                   // 16 ci x 8 rl8 = 128 rows
        const int row = ci[c] * 8 + rl8;
        arow[c] = (long long)row * Astride;
        brow[c] = (long long)row * Bstride;
    }

    auto stage = [&](int chunk, int par) {
        const int kin = k0 + chunk * 64;
        char* Lp = (char*)L + par * 65536;
#pragma unroll
        for (int c = 0; c < 2; ++c) {
            gll16(Abase + arow[c] + kin + swz8,       Lp + 0 * 16384 + ci[c] * 1024); // Ahi
            gll16(Abase + arow[c] + SEG + kin + swz8, Lp + 1 * 16384 + ci[c] * 1024); // Alo
            gll16(Bbase + brow[c] + kin + swz8,       Lp + 2 * 16384 + ci[c] * 1024); // Bhi
            gll16(Bbase + brow[c] + SEG + kin + swz8, Lp + 3 * 16384 + ci[c] * 1024); // Blo
        }
    };

    stage(0, 0);
    stage(1, 1);                          // 16 loads in flight

    for (int it = 0; it < NCHUNK; ++it) {
        const int par = it & 1;
        // wait ONLY the current buffer's 8 loads (oldest); last iter drains all
        if (it + 1 < NCHUNK) asm volatile("s_waitcnt vmcnt(8)" ::: "memory");
        else                 asm volatile("s_waitcnt vmcnt(0)" ::: "memory");
        __builtin_amdgcn_s_barrier();     // buf[par] ready for every wave

        const char* Lp = (const char*)L + par * 65536;
        bf16x8 a[2][2][4], b[2][2][2];    // [hl][ks][frag]
#pragma unroll
        for (int hl = 0; hl < 2; ++hl)
#pragma unroll
            for (int ks = 0; ks < 2; ++ks)
#pragma unroll
                for (int mf = 0; mf < 4; ++mf) {
                    const int row = wm * 64 + mf * 16 + fr;
                    a[hl][ks][mf] = *reinterpret_cast<const bf16x8*>(
                        Lp + hl * 16384 + row * 128 + 16 * ((ks * 4 + fg) ^ (fr & 7)));
                }
#pragma unroll
        for (int hl = 0; hl < 2; ++hl)
#pragma unroll
            for (int ks = 0; ks < 2; ++ks)
#pragma unroll
                for (int nf = 0; nf < 2; ++nf) {
                    const int row = wn * 32 + nf * 16 + fr;
                    b[hl][ks][nf] = *reinterpret_cast<const bf16x8*>(
                        Lp + (2 + hl) * 16384 + row * 128 + 16 * ((ks * 4 + fg) ^ (fr & 7)));
                }
        asm volatile("s_waitcnt lgkmcnt(0)" ::: "memory");
        __builtin_amdgcn_sched_barrier(0);
        __builtin_amdgcn_s_barrier();     // all waves done READING buf[par]
        __builtin_amdgcn_sched_barrier(0);
        if (it + 2 < NCHUNK) stage(it + 2, par);   // refill buf[par]
        __builtin_amdgcn_sched_barrier(0);

        __builtin_amdgcn_s_setprio(1);
#pragma unroll
        for (int ks = 0; ks < 2; ++ks)
#pragma unroll
            for (int mf = 0; mf < 4; ++mf)
#pragma unroll
                for (int nf = 0; nf < 2; ++nf) {
                    acc[mf][nf] = __builtin_amdgcn_mfma_f32_16x16x32_bf16(
                        a[0][ks][mf], b[0][ks][nf], acc[mf][nf], 0, 0, 0);   // hi.hi
                    acc[mf][nf] = __builtin_amdgcn_mfma_f32_16x16x32_bf16(
                        a[0][ks][mf], b[1][ks][nf], acc[mf][nf], 0, 0, 0);   // hi.lo
                    acc[mf][nf] = __builtin_amdgcn_mfma_f32_16x16x32_bf16(
                        a[1][ks][mf], b[0][ks][nf], acc[mf][nf], 0, 0, 0);   // lo.hi
                }
        __builtin_amdgcn_s_setprio(0);
    }
}

// ---------------------------------------------------------------------------
// prep1: fusew's prerequisites only. blockIdx-ranged:
//   [0, 7680)      w1tc: w1 f32 [j][q] -> w1T2 bf16 hi|lo [q][jcat]
//   [7680, 7936)   w2prep + bfused
// ---------------------------------------------------------------------------
__global__ __launch_bounds__(256) void prep1_kernel(
    const float* __restrict__ w1, const float* __restrict__ w2,
    const float* __restrict__ b1, const float* __restrict__ b2,
    unsigned short* __restrict__ w1T2, unsigned short* __restrict__ w2cat,
    float* __restrict__ bf) {
    __shared__ __align__(16) char smem[16640];
    const int blk = blockIdx.x;
    const int t = threadIdx.x;

    if (blk < NB_W1T) {
        float (*L)[65] = (float (*)[65])smem;
        const int q0 = (blk % (DIN / 64)) * 64, j0 = (blk / (DIN / 64)) * 64;
        const int tr = t >> 4, tc4 = (t & 15) * 4;
#pragma unroll
        for (int jj = 0; jj < 4; ++jj) {
            const int j = jj * 16 + tr;
            const float4 v = *(const float4*)(w1 + (size_t)(j0 + j) * DIN + q0 + tc4);
            L[j][tc4] = v.x; L[j][tc4 + 1] = v.y; L[j][tc4 + 2] = v.z; L[j][tc4 + 3] = v.w;
        }
        __syncthreads();
#pragma unroll
        for (int pass = 0; pass < 4; ++pass) {
            const int ql = pass * 16 + tr;
            const int jc = tc4;
            ushort4 h4, l4;
            float v0 = L[jc + 0][ql], v1 = L[jc + 1][ql], v2 = L[jc + 2][ql], v3 = L[jc + 3][ql];
            h4.x = f2bf(v0); l4.x = f2bf(v0 - bf2f(h4.x));
            h4.y = f2bf(v1); l4.y = f2bf(v1 - bf2f(h4.y));
            h4.z = f2bf(v2); l4.z = f2bf(v2 - bf2f(h4.z));
            h4.w = f2bf(v3); l4.w = f2bf(v3 - bf2f(h4.w));
            *(ushort4*)(w1T2 + (size_t)(q0 + ql) * 2048 + j0 + jc)        = h4;
            *(ushort4*)(w1T2 + (size_t)(q0 + ql) * 2048 + 1024 + j0 + jc) = l4;
        }
    } else {
        float* red = (float*)smem;
        const int p = blk - NB_W1T;
        float acc = 0.f;
#pragma unroll
        for (int j = t; j < N1_; j += 256) {
            const float v = w2[(size_t)p * N1_ + j];
            const unsigned short hi = f2bf(v);
            const unsigned short lo = f2bf(v - bf2f(hi));
            w2cat[(size_t)p * 2048 + j]        = hi;
            w2cat[(size_t)p * 2048 + 1024 + j] = lo;
            acc = fmaf(v, b1[j], acc);
        }
        red[t] = acc; __syncthreads();
        for (int s = 128; s > 0; s >>= 1) { if (t < s) red[t] += red[t + s]; __syncthreads(); }
        if (t == 0) bf[p] = red[0] + b2[p];
    }
}

// ---------------------------------------------------------------------------
// mega2: fusew (compute-bound) + roi (BW-bound) share the machine in ONE
// launch — roi's HBM streaming hides under fusew's MFMA phases.
//   [0, 480)       fusew tile (pb,qb), XCD remap 8 x 60
//   [480, 2400)    roi: CPB2=4 channels staged in LDS, 512 threads
// LDS union: fusew 128 KB | roi img 76.8 KB; + 1 KB bxc -> 129 KB (<=160).
// ---------------------------------------------------------------------------
__global__ __launch_bounds__(512, 1) void mega2_kernel(
    const float* __restrict__ z, const float* __restrict__ bboxs,
    const unsigned short* __restrict__ w2cat, const unsigned short* __restrict__ w1T2,
    unsigned short* __restrict__ W2, unsigned short* __restrict__ flat2) {
    __shared__ __align__(16) char smem[131072];
    __shared__ float bxc[64][4];
    const int blk = blockIdx.x;
    const int t = threadIdx.x;

    if (blk < NB_FW) {
        // ----- fusew: Wout[p][q] = sum_j w2[p][j] w1[j][q] -----
        unsigned short* L = (unsigned short*)smem;
        const int xcd = blk & 7, j = blk >> 3;     // j 0..59
        const int pb = j & 1;
        const int qb = xcd * 30 + (j >> 1);        // 0..239
        f32x4 acc[4][2];
#pragma unroll
        for (int i = 0; i < 4; ++i)
#pragma unroll
            for (int k = 0; k < 2; ++k) acc[i][k] = (f32x4){0.f, 0.f, 0.f, 0.f};

        gemm_core<NCH_FW, N1_>(w2cat + (long long)pb * 128 * 2048, 2048,
                               w1T2 + (long long)qb * 128 * 2048, 2048,
                               0, acc, L);

        const int w = t >> 6, lane = t & 63;
        const int wm = w >> 2, wn = w & 3;
        const int fr = lane & 15, fg = lane >> 4;
#pragma unroll
        for (int mf = 0; mf < 4; ++mf)
#pragma unroll
            for (int nf = 0; nf < 2; ++nf)
#pragma unroll
                for (int r = 0; r < 4; ++r) {
                    const int p = pb * 128 + wm * 64 + mf * 16 + fg * 4 + r;
                    const int q = qb * 128 + wn * 32 + nf * 16 + fr;
                    const float v = acc[mf][nf][r];
                    const unsigned short hi = f2bf(v);
                    const unsigned short lo = f2bf(v - bf2f(hi));
                    W2[(size_t)p * (2 * DIN) + q]       = hi;
                    W2[(size_t)p * (2 * DIN) + DIN + q] = lo;
                }
    } else {
        // ----- roi: 4 channels staged in LDS, 512 threads -----
        float* img = (float*)smem;                 // 4*4800 floats = 76.8 KB
        const int idx = blk - NB_FW;
        const int b  = idx / (C_ / CPB2);
        const int cg = idx % (C_ / CPB2);
        const float* zb = z + ((size_t)b * C_ + (size_t)cg * CPB2) * (size_t)(T_ * IMG)
                            + (size_t)(T_ - 1) * IMG;
#pragma unroll
        for (int c = 0; c < CPB2; ++c) {
            const float4* src = (const float4*)(zb + (size_t)c * (T_ * IMG));
            float4* dst = (float4*)(img + c * IMG);
            for (int i = t; i < IMG / 4; i += 512) dst[i] = src[i];
        }
        if (t < 64) {
            const float* bp = bboxs + ((size_t)b * 64 + t) * 4;
            const float v0 = bp[0], v1 = bp[1], v2 = bp[2], v3 = bp[3];
            bxc[t][0] = isnan(v0) ? 0.f : v0;
            bxc[t][1] = isnan(v1) ? 0.f : v1;
            bxc[t][2] = isnan(v2) ? 0.f : v2;
            bxc[t][3] = isnan(v3) ? 0.f : v3;
        }
        __syncthreads();

        const int p = t & 63, mh = t >> 6;         // mh 0..7
        const int gy = p >> 3, gx = p & 7;
        for (int mq = 0; mq < 8; ++mq) {
            const int m = mq * 8 + mh;
            const float x1 = bxc[m][0] * 0.125f - 0.5f;
            const float y1 = bxc[m][1] * 0.125f - 0.5f;
            const float x2 = bxc[m][2] * 0.125f - 0.5f;
            const float y2 = bxc[m][3] * 0.125f - 0.5f;
            const float bw = (x2 - x1) * (1.0f / OS_);
            const float bh = (y2 - y1) * (1.0f / OS_);
            const float X = x1 + ((float)gx + 0.5f) * bw;
            const float Y = y1 + ((float)gy + 0.5f) * bh;
            const bool valid = (Y >= -1.0f) && (Y <= (float)FY_) &&
                               (X >= -1.0f) && (X <= (float)FX_);
            const float yc = fminf(fmaxf(Y, 0.f), (float)(FY_ - 1));
            const float xc = fminf(fmaxf(X, 0.f), (float)(FX_ - 1));
            const float y0f = floorf(yc), x0f = floorf(xc);
            const int y0 = (int)y0f, x0 = (int)x0f;
            const int y1i = min(y0 + 1, FY_ - 1);
            const int x1i = min(x0 + 1, FX_ - 1);
            const float ly = yc - y0f, lx = xc - x0f;
            const float hy = 1.f - ly,  hx = 1.f - lx;
            float w00 = hy * hx, w01 = hy * lx, w10 = ly * hx, w11 = ly * lx;
            if (!valid) { w00 = 0.f; w01 = 0.f; w10 = 0.f; w11 = 0.f; }
            const int i00 = y0 * FX_ + x0, i01 = y0 * FX_ + x1i;
            const int i10 = y1i * FX_ + x0, i11 = y1i * FX_ + x1i;
            unsigned short* fo = flat2 + (size_t)(b * 64 + m) * (2 * DIN)
                                       + cg * (CPB2 * 64) + p;
#pragma unroll
            for (int c = 0; c < CPB2; ++c) {
                const float* f = img + c * IMG;
                const float v = w00 * f[i00] + w01 * f[i01] + w10 * f[i10] + w11 * f[i11];
                const unsigned short hi = f2bf(v);
                const unsigned short lo = f2bf(v - bf2f(hi));
                fo[c * 64]       = hi;
                fo[DIN + c * 64] = lo;
            }
        }
    }
}

// ---------------------------------------------------------------------------
// zz partials: part[sp][m][n]. 128x128 tile, 512 thr, v5 core, K split 16.
// XCD remap (bijective, 256 = 8 x 32): 8 mb sharing a (nb,sp) B-tile are
// temporally adjacent on one XCD.
// ---------------------------------------------------------------------------
__global__ __launch_bounds__(512, 1) void zz_mfma(const unsigned short* __restrict__ flat2,
                                                  const unsigned short* __restrict__ W2,
                                                  float* __restrict__ part) {
    __shared__ __align__(16) unsigned short L[2 * 4 * 128 * 64];   // 128 KB
    const int bid = blockIdx.x;
    const int xcd = bid & 7, j = bid >> 3;     // j 0..31
    const int mb = j & 7;
    const int pair = xcd * 4 + (j >> 3);       // 0..31
    const int nb = pair & 1, sp = pair >> 1;   // nb 0..1, sp 0..15
    f32x4 acc[4][2];
#pragma unroll
    for (int i = 0; i < 4; ++i)
#pragma unroll
        for (int k = 0; k < 2; ++k) acc[i][k] = (f32x4){0.f, 0.f, 0.f, 0.f};

    gemm_core<NCH_ZZ, DIN>(flat2 + (long long)mb * 128 * (2 * DIN), 2 * DIN,
                           W2 + (long long)nb * 128 * (2 * DIN), 2 * DIN,
                           sp * (NCH_ZZ * 64), acc, L);

    float* po = part + (size_t)sp * (M_ * N2_);
    const int t = threadIdx.x;
    const int w = t >> 6, lane = t & 63;
    const int wm = w >> 2, wn = w & 3;
    const int fr = lane & 15, fg = lane >> 4;
#pragma unroll
    for (int mf = 0; mf < 4; ++mf)
#pragma unroll
        for (int nf = 0; nf < 2; ++nf)
#pragma unroll
            for (int r = 0; r < 4; ++r) {
                const int m = mb * 128 + wm * 64 + mf * 16 + fg * 4 + r;
                const int n = nb * 128 + wn * 32 + nf * 16 + fr;
                po[(size_t)m * N2_ + n] = acc[mf][nf][r];
            }
}

// ---------------------------------------------------------------------------
// Fused reduce + cluster: one block per sample m, 256 threads (t = n).
// ---------------------------------------------------------------------------
__global__ __launch_bounds__(256) void reduce_cluster_kernel(
    const float* __restrict__ part, const float* __restrict__ bf,
    const float* __restrict__ cent,
    float* __restrict__ out_zz, float* __restrict__ out_s, float* __restrict__ out_c) {
    __shared__ float row[N2_];
    const int m = blockIdx.x, t = threadIdx.x;
    float a = bf[t];
#pragma unroll
    for (int s = 0; s < SPLITK; ++s) a += part[(size_t)s * (M_ * N2_) + (size_t)m * N2_ + t];
    out_zz[(size_t)m * N2_ + t] = a;
    row[t] = a;
    __syncthreads();
    if (t < 64) {
        const float* cr = cent + (size_t)t * N2_;
        float dot = 0.f, c2 = 0.f, z2 = 0.f;
        for (int d = 0; d < N2_; ++d) {
            const float zv = row[d], cv = cr[d];
            dot = fmaf(zv, cv, dot);
            c2  = fmaf(cv, cv, c2);
            z2  = fmaf(zv, zv, z2);
        }
        const float nrm = sqrtf(fmaxf(z2 + c2 - 2.f * dot, 0.f));
        const float su = 1.0f / (1.0f + nrm);
        float ssum = su;
#pragma unroll
        for (int mk = 1; mk < 64; mk <<= 1) ssum += __shfl_xor(ssum, mk, 64);
        const float s = su / ssum;
        out_s[(size_t)m * 64 + t] = s;
        float bv = s; int bi = t;
#pragma unroll
        for (int mk = 1; mk < 64; mk <<= 1) {
            const float ov = __shfl_xor(bv, mk, 64);
            const int   oi = __shfl_xor(bi, mk, 64);
            if (ov > bv || (ov == bv && oi < bi)) { bv = ov; bi = oi; }
        }
        if (t == 0) out_c[m] = (float)bi;
    }
}

// ---------------------------------------------------------------------------
extern "C" void kernel_launch(void* const* d_in, const int* in_sizes, int n_in,
                              void* d_out, int out_size, void* d_ws, size_t ws_size,
                              hipStream_t stream) {
    const float* z     = (const float*)d_in[0];
    const float* bboxs = (const float*)d_in[1];
    const float* w1    = (const float*)d_in[2];
    const float* b1    = (const float*)d_in[3];
    const float* w2    = (const float*)d_in[4];
    const float* b2    = (const float*)d_in[5];
    const float* cent  = (const float*)d_in[6];
    float* out = (float*)d_out;
    float* out_zz = out;                                        // 1024*256
    float* out_s  = out + (size_t)M_ * N2_;                     // 1024*64
    float* out_c  = out + (size_t)M_ * N2_ + (size_t)M_ * K_;   // 1024

    char* ws = (char*)d_ws;                                     // ws >= 1.1 GB
    unsigned short* w1T2   = (unsigned short*)(ws);                  // 125,829,120 B
    unsigned short* flat2  = (unsigned short*)(ws + 125829120u);     // 125,829,120 B
    unsigned short* W2     = (unsigned short*)(ws + 251658240u);     //  31,457,280 B
    float*          part   = (float*)(ws + 283115520u);              //  16,777,216 B
    unsigned short* w2cat  = (unsigned short*)(ws + 316669952u);     //   1,048,576 B
    float*          bfused = (float*)(ws + 317718528u);              //       1,024 B

    prep1_kernel<<<dim3(NB_W1T + NB_W2P), dim3(256), 0, stream>>>(
        w1, w2, b1, b2, w1T2, w2cat, bfused);
    mega2_kernel<<<dim3(NB_FW + NB_ROI2), dim3(512), 0, stream>>>(
        z, bboxs, w2cat, w1T2, W2, flat2);
    zz_mfma<<<dim3(256), dim3(512), 0, stream>>>(flat2, W2, part);
    reduce_cluster_kernel<<<dim3(1024), dim3(256), 0, stream>>>(part, bfused, cent,
                                                                out_zz, out_s, out_c);
}

// Round 13
// 229.008 us; speedup vs baseline: 1.1567x; 1.1567x over previous
//
#include <hip/hip_runtime.h>
#include <hip/hip_bf16.h>

// Problem dims (fixed by reference)
static constexpr int B_  = 16;
static constexpr int SN_ = 64;
static constexpr int C_  = 480;
static constexpr int T_  = 2;
static constexpr int FY_ = 60;
static constexpr int FX_ = 80;
static constexpr int OS_ = 8;
static constexpr int DIN = 30720;            // C*OS*OS
static constexpr int M_  = 1024;             // B*SN
static constexpr int N1_ = 1024;
static constexpr int N2_ = 256;
static constexpr int K_  = 64;               // clusters
static constexpr int SPLITK = 16;
static constexpr int NCH_ZZ = (DIN / 64) / SPLITK;  // 30 chunks per split
static constexpr int NCH_FW = N1_ / 64;             // 16 chunks
static constexpr int CPB = 2;                    // roi channels per block
static constexpr int IMG = FY_ * FX_;            // 4800
// prep mega-kernel block ranges
static constexpr int NB_ROI = 16 * (C_ / CPB);   // 3840
static constexpr int NB_W1T = (DIN / 64) * (N1_ / 64);  // 7680
static constexpr int NB_W2P = N2_;               // 256

typedef __bf16 bf16x8 __attribute__((ext_vector_type(8)));
typedef float  f32x4  __attribute__((ext_vector_type(4)));
typedef unsigned int u32_as1 __attribute__((address_space(1)));
typedef unsigned int u32_as3 __attribute__((address_space(3)));

__device__ __forceinline__ float bf2f(unsigned short u) {
    union { unsigned int i; float f; } v; v.i = ((unsigned int)u) << 16; return v.f;
}
// RNE f32 -> bf16 bits (inputs finite here)
__device__ __forceinline__ unsigned short f2bf(float f) {
    unsigned int u = __float_as_uint(f);
    u = u + 0x7FFFu + ((u >> 16) & 1u);
    return (unsigned short)(u >> 16);
}
__device__ __forceinline__ void gll16(const void* g, void* l) {
    __builtin_amdgcn_global_load_lds((const u32_as1*)g, (u32_as3*)l, 16, 0, 0);
}

// ---------------------------------------------------------------------------
// MFMA GEMM core v5 (round-11 verbatim) — 4-stage/3-product chunking +
// depth-2 counted vmcnt. Per K-chunk: stage {Ahi, Alo, Bhi, Blo} once
// (8 gll16/thread), compute Ahi.Bhi + Ahi.Blo + Alo.Bhi.
// 512 threads = 8 waves (2m x 4n), tile 128x128, wave-tile 64x32.
// LDS = 2 x 4 x [128][64] bf16 = 128 KB, XOR-swizzled k-slots.
// vmcnt(8) waits current buffer only; WAR guarded by lgkm(0)+SB+barrier.
// ---------------------------------------------------------------------------
template<int NCHUNK, int SEG>
__device__ __forceinline__ void gemm_core(
    const unsigned short* __restrict__ Abase, long long Astride,
    const unsigned short* __restrict__ Bbase, long long Bstride,
    int k0, f32x4 (&acc)[4][2], unsigned short* L)   // L: 2*4*128*64 elems
{
    const int t = threadIdx.x;
    const int w = t >> 6, lane = t & 63;
    const int rl8 = lane >> 3, slot = lane & 7;
    const int wm = w >> 2, wn = w & 3;
    const int fr = lane & 15, fg = lane >> 4;
    const int swz8 = (slot ^ rl8) * 8;       // row&7 == rl8 for staging rows

    long long arow[2], brow[2];
    int ci[2];
#pragma unroll
    for (int c = 0; c < 2; ++c) {
        ci[c] = w * 2 + c;                   // 16 ci x 8 rl8 = 128 rows
        const int row = ci[c] * 8 + rl8;
        arow[c] = (long long)row * Astride;
        brow[c] = (long long)row * Bstride;
    }

    auto stage = [&](int chunk, int par) {
        const int kin = k0 + chunk * 64;
        char* Lp = (char*)L + par * 65536;
#pragma unroll
        for (int c = 0; c < 2; ++c) {
            gll16(Abase + arow[c] + kin + swz8,       Lp + 0 * 16384 + ci[c] * 1024); // Ahi
            gll16(Abase + arow[c] + SEG + kin + swz8, Lp + 1 * 16384 + ci[c] * 1024); // Alo
            gll16(Bbase + brow[c] + kin + swz8,       Lp + 2 * 16384 + ci[c] * 1024); // Bhi
            gll16(Bbase + brow[c] + SEG + kin + swz8, Lp + 3 * 16384 + ci[c] * 1024); // Blo
        }
    };

    stage(0, 0);
    stage(1, 1);                          // 16 loads in flight

    for (int it = 0; it < NCHUNK; ++it) {
        const int par = it & 1;
        // wait ONLY the current buffer's 8 loads (oldest); last iter drains all
        if (it + 1 < NCHUNK) asm volatile("s_waitcnt vmcnt(8)" ::: "memory");
        else                 asm volatile("s_waitcnt vmcnt(0)" ::: "memory");
        __builtin_amdgcn_s_barrier();     // buf[par] ready for every wave

        const char* Lp = (const char*)L + par * 65536;
        bf16x8 a[2][2][4], b[2][2][2];    // [hl][ks][frag]
#pragma unroll
        for (int hl = 0; hl < 2; ++hl)
#pragma unroll
            for (int ks = 0; ks < 2; ++ks)
#pragma unroll
                for (int mf = 0; mf < 4; ++mf) {
                    const int row = wm * 64 + mf * 16 + fr;
                    a[hl][ks][mf] = *reinterpret_cast<const bf16x8*>(
                        Lp + hl * 16384 + row * 128 + 16 * ((ks * 4 + fg) ^ (fr & 7)));
                }
#pragma unroll
        for (int hl = 0; hl < 2; ++hl)
#pragma unroll
            for (int ks = 0; ks < 2; ++ks)
#pragma unroll
                for (int nf = 0; nf < 2; ++nf) {
                    const int row = wn * 32 + nf * 16 + fr;
                    b[hl][ks][nf] = *reinterpret_cast<const bf16x8*>(
                        Lp + (2 + hl) * 16384 + row * 128 + 16 * ((ks * 4 + fg) ^ (fr & 7)));
                }
        asm volatile("s_waitcnt lgkmcnt(0)" ::: "memory");
        __builtin_amdgcn_sched_barrier(0);
        __builtin_amdgcn_s_barrier();     // all waves done READING buf[par]
        __builtin_amdgcn_sched_barrier(0);
        if (it + 2 < NCHUNK) stage(it + 2, par);   // refill buf[par]
        __builtin_amdgcn_sched_barrier(0);

        __builtin_amdgcn_s_setprio(1);
#pragma unroll
        for (int ks = 0; ks < 2; ++ks)
#pragma unroll
            for (int mf = 0; mf < 4; ++mf)
#pragma unroll
                for (int nf = 0; nf < 2; ++nf) {
                    acc[mf][nf] = __builtin_amdgcn_mfma_f32_16x16x32_bf16(
                        a[0][ks][mf], b[0][ks][nf], acc[mf][nf], 0, 0, 0);   // hi.hi
                    acc[mf][nf] = __builtin_amdgcn_mfma_f32_16x16x32_bf16(
                        a[0][ks][mf], b[1][ks][nf], acc[mf][nf], 0, 0, 0);   // hi.lo
                    acc[mf][nf] = __builtin_amdgcn_mfma_f32_16x16x32_bf16(
                        a[1][ks][mf], b[0][ks][nf], acc[mf][nf], 0, 0, 0);   // lo.hi
                }
        __builtin_amdgcn_s_setprio(0);
    }
}

// ---------------------------------------------------------------------------
// PREP mega-kernel (round-9/11 verbatim): blockIdx-ranged dispatch of three
// independent memory-bound preps sharing HBM BW. Union LDS 39,424 B
// -> 4 blocks/CU (roi occupancy is what round-12's merge destroyed).
// ---------------------------------------------------------------------------
__global__ __launch_bounds__(256) void prep_kernel(
    const float* __restrict__ z, const float* __restrict__ bboxs,
    const float* __restrict__ w1, const float* __restrict__ w2,
    const float* __restrict__ b1, const float* __restrict__ b2,
    unsigned short* __restrict__ flat2, unsigned short* __restrict__ w1T2,
    unsigned short* __restrict__ w2cat, float* __restrict__ bf) {
    __shared__ __align__(16) char smem[39424];
    const int blk = blockIdx.x;
    const int t = threadIdx.x;

    if (blk < NB_ROI) {
        float* img = (float*)smem;                       // 2*4800 floats
        float (*bxc)[4] = (float (*)[4])(smem + 38400);  // 64*4 floats
        const int b  = blk / (C_ / CPB);
        const int cg = blk % (C_ / CPB);
        const float* zb = z + ((size_t)b * C_ + (size_t)cg * CPB) * (size_t)(T_ * IMG)
                            + (size_t)(T_ - 1) * IMG;
#pragma unroll
        for (int c = 0; c < CPB; ++c) {
            const float4* src = (const float4*)(zb + (size_t)c * (T_ * IMG));
            float4* dst = (float4*)(img + c * IMG);
            for (int i = t; i < IMG / 4; i += 256) dst[i] = src[i];
        }
        if (t < 64) {
            const float* bp = bboxs + ((size_t)b * 64 + t) * 4;
            const float v0 = bp[0], v1 = bp[1], v2 = bp[2], v3 = bp[3];
            bxc[t][0] = isnan(v0) ? 0.f : v0;
            bxc[t][1] = isnan(v1) ? 0.f : v1;
            bxc[t][2] = isnan(v2) ? 0.f : v2;
            bxc[t][3] = isnan(v3) ? 0.f : v3;
        }
        __syncthreads();

        const int p = t & 63, mh = t >> 6;
        const int gy = p >> 3, gx = p & 7;
        for (int mq = 0; mq < 16; ++mq) {
            const int m = mq * 4 + mh;
            const float x1 = bxc[m][0] * 0.125f - 0.5f;
            const float y1 = bxc[m][1] * 0.125f - 0.5f;
            const float x2 = bxc[m][2] * 0.125f - 0.5f;
            const float y2 = bxc[m][3] * 0.125f - 0.5f;
            const float bw = (x2 - x1) * (1.0f / OS_);
            const float bh = (y2 - y1) * (1.0f / OS_);
            const float X = x1 + ((float)gx + 0.5f) * bw;
            const float Y = y1 + ((float)gy + 0.5f) * bh;
            const bool valid = (Y >= -1.0f) && (Y <= (float)FY_) &&
                               (X >= -1.0f) && (X <= (float)FX_);
            const float yc = fminf(fmaxf(Y, 0.f), (float)(FY_ - 1));
            const float xc = fminf(fmaxf(X, 0.f), (float)(FX_ - 1));
            const float y0f = floorf(yc), x0f = floorf(xc);
            const int y0 = (int)y0f, x0 = (int)x0f;
            const int y1i = min(y0 + 1, FY_ - 1);
            const int x1i = min(x0 + 1, FX_ - 1);
            const float ly = yc - y0f, lx = xc - x0f;
            const float hy = 1.f - ly,  hx = 1.f - lx;
            float w00 = hy * hx, w01 = hy * lx, w10 = ly * hx, w11 = ly * lx;
            if (!valid) { w00 = 0.f; w01 = 0.f; w10 = 0.f; w11 = 0.f; }
            const int i00 = y0 * FX_ + x0, i01 = y0 * FX_ + x1i;
            const int i10 = y1i * FX_ + x0, i11 = y1i * FX_ + x1i;
            unsigned short* fo = flat2 + (size_t)(b * 64 + m) * (2 * DIN)
                                       + cg * (CPB * 64) + p;
#pragma unroll
            for (int c = 0; c < CPB; ++c) {
                const float* f = img + c * IMG;
                const float v = w00 * f[i00] + w01 * f[i01] + w10 * f[i10] + w11 * f[i11];
                const unsigned short hi = f2bf(v);
                const unsigned short lo = f2bf(v - bf2f(hi));
                fo[c * 64]       = hi;
                fo[DIN + c * 64] = lo;
            }
        }
    } else if (blk < NB_ROI + NB_W1T) {
        float (*L)[65] = (float (*)[65])smem;
        const int idx = blk - NB_ROI;
        const int q0 = (idx % (DIN / 64)) * 64, j0 = (idx / (DIN / 64)) * 64;
        const int tr = t >> 4, tc4 = (t & 15) * 4;
#pragma unroll
        for (int jj = 0; jj < 4; ++jj) {
            const int j = jj * 16 + tr;
            const float4 v = *(const float4*)(w1 + (size_t)(j0 + j) * DIN + q0 + tc4);
            L[j][tc4] = v.x; L[j][tc4 + 1] = v.y; L[j][tc4 + 2] = v.z; L[j][tc4 + 3] = v.w;
        }
        __syncthreads();
#pragma unroll
        for (int pass = 0; pass < 4; ++pass) {
            const int ql = pass * 16 + tr;
            const int jc = tc4;
            ushort4 h4, l4;
            float v0 = L[jc + 0][ql], v1 = L[jc + 1][ql], v2 = L[jc + 2][ql], v3 = L[jc + 3][ql];
            h4.x = f2bf(v0); l4.x = f2bf(v0 - bf2f(h4.x));
            h4.y = f2bf(v1); l4.y = f2bf(v1 - bf2f(h4.y));
            h4.z = f2bf(v2); l4.z = f2bf(v2 - bf2f(h4.z));
            h4.w = f2bf(v3); l4.w = f2bf(v3 - bf2f(h4.w));
            *(ushort4*)(w1T2 + (size_t)(q0 + ql) * 2048 + j0 + jc)        = h4;
            *(ushort4*)(w1T2 + (size_t)(q0 + ql) * 2048 + 1024 + j0 + jc) = l4;
        }
    } else {
        float* red = (float*)smem;
        const int p = blk - (NB_ROI + NB_W1T);
        float acc = 0.f;
#pragma unroll
        for (int j = t; j < N1_; j += 256) {
            const float v = w2[(size_t)p * N1_ + j];
            const unsigned short hi = f2bf(v);
            const unsigned short lo = f2bf(v - bf2f(hi));
            w2cat[(size_t)p * 2048 + j]        = hi;
            w2cat[(size_t)p * 2048 + 1024 + j] = lo;
            acc = fmaf(v, b1[j], acc);
        }
        red[t] = acc; __syncthreads();
        for (int s = 128; s > 0; s >>= 1) { if (t < s) red[t] += red[t + s]; __syncthreads(); }
        if (t == 0) bf[p] = red[0] + b2[p];
    }
}

// ---------------------------------------------------------------------------
// fusew: Wout[p][q] = sum_j w2[p][j] w1[j][q]. 128x128 tile, 512 thr, v5 core.
// XCD-aware remap: pb twins (sharing the w1T2 B-tile) temporally adjacent on
// one XCD. grid 480 (= 8 x 60, bijective).
// ---------------------------------------------------------------------------
__global__ __launch_bounds__(512, 1) void fusew_mfma(const unsigned short* __restrict__ w2cat,
                                                     const unsigned short* __restrict__ w1T2,
                                                     unsigned short* __restrict__ W2) {
    __shared__ __align__(16) unsigned short L[2 * 4 * 128 * 64];   // 128 KB
    const int bid = blockIdx.x;
    const int xcd = bid & 7, j = bid >> 3;     // j 0..59
    const int pb = j & 1;
    const int qb = xcd * 30 + (j >> 1);        // 0..239
    f32x4 acc[4][2];
#pragma unroll
    for (int i = 0; i < 4; ++i)
#pragma unroll
        for (int k = 0; k < 2; ++k) acc[i][k] = (f32x4){0.f, 0.f, 0.f, 0.f};

    gemm_core<NCH_FW, N1_>(w2cat + (long long)pb * 128 * 2048, 2048,
                           w1T2 + (long long)qb * 128 * 2048, 2048,
                           0, acc, L);

    const int t = threadIdx.x;
    const int w = t >> 6, lane = t & 63;
    const int wm = w >> 2, wn = w & 3;
    const int fr = lane & 15, fg = lane >> 4;
#pragma unroll
    for (int mf = 0; mf < 4; ++mf)
#pragma unroll
        for (int nf = 0; nf < 2; ++nf)
#pragma unroll
            for (int r = 0; r < 4; ++r) {
                const int p = pb * 128 + wm * 64 + mf * 16 + fg * 4 + r;
                const int q = qb * 128 + wn * 32 + nf * 16 + fr;
                const float v = acc[mf][nf][r];
                const unsigned short hi = f2bf(v);
                const unsigned short lo = f2bf(v - bf2f(hi));
                W2[(size_t)p * (2 * DIN) + q]       = hi;
                W2[(size_t)p * (2 * DIN) + DIN + q] = lo;
            }
}

// ---------------------------------------------------------------------------
// zz partials: part[sp][m][n]. 128x128 tile, 512 thr, v5 core, K split 16.
// grid 256 = exactly 1 block/CU, single round. XCD remap (bijective,
// 256 = 8 x 32): the 8 mb blocks sharing a (nb,sp) B-tile are temporally
// adjacent on one XCD.
// ---------------------------------------------------------------------------
__global__ __launch_bounds__(512, 1) void zz_mfma(const unsigned short* __restrict__ flat2,
                                                  const unsigned short* __restrict__ W2,
                                                  float* __restrict__ part) {
    __shared__ __align__(16) unsigned short L[2 * 4 * 128 * 64];   // 128 KB
    const int bid = blockIdx.x;
    const int xcd = bid & 7, j = bid >> 3;     // j 0..31
    const int mb = j & 7;
    const int pair = xcd * 4 + (j >> 3);       // 0..31
    const int nb = pair & 1, sp = pair >> 1;   // nb 0..1, sp 0..15
    f32x4 acc[4][2];
#pragma unroll
    for (int i = 0; i < 4; ++i)
#pragma unroll
        for (int k = 0; k < 2; ++k) acc[i][k] = (f32x4){0.f, 0.f, 0.f, 0.f};

    gemm_core<NCH_ZZ, DIN>(flat2 + (long long)mb * 128 * (2 * DIN), 2 * DIN,
                           W2 + (long long)nb * 128 * (2 * DIN), 2 * DIN,
                           sp * (NCH_ZZ * 64), acc, L);

    float* po = part + (size_t)sp * (M_ * N2_);
    const int t = threadIdx.x;
    const int w = t >> 6, lane = t & 63;
    const int wm = w >> 2, wn = w & 3;
    const int fr = lane & 15, fg = lane >> 4;
#pragma unroll
    for (int mf = 0; mf < 4; ++mf)
#pragma unroll
        for (int nf = 0; nf < 2; ++nf)
#pragma unroll
            for (int r = 0; r < 4; ++r) {
                const int m = mb * 128 + wm * 64 + mf * 16 + fg * 4 + r;
                const int n = nb * 128 + wn * 32 + nf * 16 + fr;
                po[(size_t)m * N2_ + n] = acc[mf][nf][r];
            }
}

// ---------------------------------------------------------------------------
// Fused reduce + cluster: one block per sample m, 256 threads (t = n).
// ---------------------------------------------------------------------------
__global__ __launch_bounds__(256) void reduce_cluster_kernel(
    const float* __restrict__ part, const float* __restrict__ bf,
    const float* __restrict__ cent,
    float* __restrict__ out_zz, float* __restrict__ out_s, float* __restrict__ out_c) {
    __shared__ float row[N2_];
    const int m = blockIdx.x, t = threadIdx.x;
    float a = bf[t];
#pragma unroll
    for (int s = 0; s < SPLITK; ++s) a += part[(size_t)s * (M_ * N2_) + (size_t)m * N2_ + t];
    out_zz[(size_t)m * N2_ + t] = a;
    row[t] = a;
    __syncthreads();
    if (t < 64) {
        const float* cr = cent + (size_t)t * N2_;
        float dot = 0.f, c2 = 0.f, z2 = 0.f;
        for (int d = 0; d < N2_; ++d) {
            const float zv = row[d], cv = cr[d];
            dot = fmaf(zv, cv, dot);
            c2  = fmaf(cv, cv, c2);
            z2  = fmaf(zv, zv, z2);
        }
        const float nrm = sqrtf(fmaxf(z2 + c2 - 2.f * dot, 0.f));
        const float su = 1.0f / (1.0f + nrm);
        float ssum = su;
#pragma unroll
        for (int mk = 1; mk < 64; mk <<= 1) ssum += __shfl_xor(ssum, mk, 64);
        const float s = su / ssum;
        out_s[(size_t)m * 64 + t] = s;
        float bv = s; int bi = t;
#pragma unroll
        for (int mk = 1; mk < 64; mk <<= 1) {
            const float ov = __shfl_xor(bv, mk, 64);
            const int   oi = __shfl_xor(bi, mk, 64);
            if (ov > bv || (ov == bv && oi < bi)) { bv = ov; bi = oi; }
        }
        if (t == 0) out_c[m] = (float)bi;
    }
}

// ---------------------------------------------------------------------------
extern "C" void kernel_launch(void* const* d_in, const int* in_sizes, int n_in,
                              void* d_out, int out_size, void* d_ws, size_t ws_size,
                              hipStream_t stream) {
    const float* z     = (const float*)d_in[0];
    const float* bboxs = (const float*)d_in[1];
    const float* w1    = (const float*)d_in[2];
    const float* b1    = (const float*)d_in[3];
    const float* w2    = (const float*)d_in[4];
    const float* b2    = (const float*)d_in[5];
    const float* cent  = (const float*)d_in[6];
    float* out = (float*)d_out;
    float* out_zz = out;                                        // 1024*256
    float* out_s  = out + (size_t)M_ * N2_;                     // 1024*64
    float* out_c  = out + (size_t)M_ * N2_ + (size_t)M_ * K_;   // 1024

    char* ws = (char*)d_ws;                                     // ws >= 1.1 GB
    unsigned short* w1T2   = (unsigned short*)(ws);                  // 125,829,120 B
    unsigned short* flat2  = (unsigned short*)(ws + 125829120u);     // 125,829,120 B
    unsigned short* W2     = (unsigned short*)(ws + 251658240u);     //  31,457,280 B
    float*          part   = (float*)(ws + 283115520u);              //  16,777,216 B
    unsigned short* w2cat  = (unsigned short*)(ws + 316669952u);     //   1,048,576 B
    float*          bfused = (float*)(ws + 317718528u);              //       1,024 B

    prep_kernel<<<dim3(NB_ROI + NB_W1T + NB_W2P), dim3(256), 0, stream>>>(
        z, bboxs, w1, w2, b1, b2, flat2, w1T2, w2cat, bfused);
    fusew_mfma<<<dim3(480), dim3(512), 0, stream>>>(w2cat, w1T2, W2);
    zz_mfma<<<dim3(256), dim3(512), 0, stream>>>(flat2, W2, part);
    reduce_cluster_kernel<<<dim3(1024), dim3(256), 0, stream>>>(part, bfused, cent,
                                                                out_zz, out_s, out_c);
}

// Round 14
// 228.366 us; speedup vs baseline: 1.1599x; 1.0028x over previous
//
#include <hip/hip_runtime.h>
#include <hip/hip_bf16.h>

// Problem dims (fixed by reference)
static constexpr int B_  = 16;
static constexpr int SN_ = 64;
static constexpr int C_  = 480;
static constexpr int T_  = 2;
static constexpr int FY_ = 60;
static constexpr int FX_ = 80;
static constexpr int OS_ = 8;
static constexpr int DIN = 30720;            // C*OS*OS
static constexpr int M_  = 1024;             // B*SN
static constexpr int N1_ = 1024;
static constexpr int N2_ = 256;
static constexpr int K_  = 64;               // clusters
static constexpr int SPLITK = 16;
static constexpr int NCH_ZZ = (DIN / 64) / SPLITK;  // 30 chunks per split (BK=64 core)
static constexpr int NCH_FW = N1_ / 32;             // 32 chunks (BK=32 core)
static constexpr int CPB = 2;                    // roi channels per block
static constexpr int IMG = FY_ * FX_;            // 4800
// prep1 block ranges (256 thr)
static constexpr int NB_W1T = (DIN / 64) * (N1_ / 64);  // 7680
static constexpr int NB_W2P = N2_;                      // 256
// mega2 block ranges (512 thr)
static constexpr int NB_FW  = 480;               // fusew tiles (8 x 60 remap)
static constexpr int NB_ROI = 16 * (C_ / CPB);   // 3840

typedef __bf16 bf16x8 __attribute__((ext_vector_type(8)));
typedef float  f32x4  __attribute__((ext_vector_type(4)));
typedef unsigned int u32_as1 __attribute__((address_space(1)));
typedef unsigned int u32_as3 __attribute__((address_space(3)));

__device__ __forceinline__ float bf2f(unsigned short u) {
    union { unsigned int i; float f; } v; v.i = ((unsigned int)u) << 16; return v.f;
}
// RNE f32 -> bf16 bits (inputs finite here)
__device__ __forceinline__ unsigned short f2bf(float f) {
    unsigned int u = __float_as_uint(f);
    u = u + 0x7FFFu + ((u >> 16) & 1u);
    return (unsigned short)(u >> 16);
}
__device__ __forceinline__ void gll16(const void* g, void* l) {
    __builtin_amdgcn_global_load_lds((const u32_as1*)g, (u32_as3*)l, 16, 0, 0);
}

// ---------------------------------------------------------------------------
// MFMA GEMM core v5 (round-13 verbatim, BK=64, 128 KB LDS) — used by zz.
// 4-stage/3-product chunking + depth-2 counted vmcnt. 512 thr, 8 waves
// (2m x 4n), tile 128x128. vmcnt(8) waits current buffer only; WAR guarded
// by lgkm(0)+SB+barrier (rule #18).
// ---------------------------------------------------------------------------
template<int NCHUNK, int SEG>
__device__ __forceinline__ void gemm_core(
    const unsigned short* __restrict__ Abase, long long Astride,
    const unsigned short* __restrict__ Bbase, long long Bstride,
    int k0, f32x4 (&acc)[4][2], unsigned short* L)   // L: 2*4*128*64 elems
{
    const int t = threadIdx.x;
    const int w = t >> 6, lane = t & 63;
    const int rl8 = lane >> 3, slot = lane & 7;
    const int wm = w >> 2, wn = w & 3;
    const int fr = lane & 15, fg = lane >> 4;
    const int swz8 = (slot ^ rl8) * 8;       // row&7 == rl8 for staging rows

    long long arow[2], brow[2];
    int ci[2];
#pragma unroll
    for (int c = 0; c < 2; ++c) {
        ci[c] = w * 2 + c;                   // 16 ci x 8 rl8 = 128 rows
        const int row = ci[c] * 8 + rl8;
        arow[c] = (long long)row * Astride;
        brow[c] = (long long)row * Bstride;
    }

    auto stage = [&](int chunk, int par) {
        const int kin = k0 + chunk * 64;
        char* Lp = (char*)L + par * 65536;
#pragma unroll
        for (int c = 0; c < 2; ++c) {
            gll16(Abase + arow[c] + kin + swz8,       Lp + 0 * 16384 + ci[c] * 1024); // Ahi
            gll16(Abase + arow[c] + SEG + kin + swz8, Lp + 1 * 16384 + ci[c] * 1024); // Alo
            gll16(Bbase + brow[c] + kin + swz8,       Lp + 2 * 16384 + ci[c] * 1024); // Bhi
            gll16(Bbase + brow[c] + SEG + kin + swz8, Lp + 3 * 16384 + ci[c] * 1024); // Blo
        }
    };

    stage(0, 0);
    stage(1, 1);                          // 16 loads in flight

    for (int it = 0; it < NCHUNK; ++it) {
        const int par = it & 1;
        if (it + 1 < NCHUNK) asm volatile("s_waitcnt vmcnt(8)" ::: "memory");
        else                 asm volatile("s_waitcnt vmcnt(0)" ::: "memory");
        __builtin_amdgcn_s_barrier();     // buf[par] ready for every wave

        const char* Lp = (const char*)L + par * 65536;
        bf16x8 a[2][2][4], b[2][2][2];    // [hl][ks][frag]
#pragma unroll
        for (int hl = 0; hl < 2; ++hl)
#pragma unroll
            for (int ks = 0; ks < 2; ++ks)
#pragma unroll
                for (int mf = 0; mf < 4; ++mf) {
                    const int row = wm * 64 + mf * 16 + fr;
                    a[hl][ks][mf] = *reinterpret_cast<const bf16x8*>(
                        Lp + hl * 16384 + row * 128 + 16 * ((ks * 4 + fg) ^ (fr & 7)));
                }
#pragma unroll
        for (int hl = 0; hl < 2; ++hl)
#pragma unroll
            for (int ks = 0; ks < 2; ++ks)
#pragma unroll
                for (int nf = 0; nf < 2; ++nf) {
                    const int row = wn * 32 + nf * 16 + fr;
                    b[hl][ks][nf] = *reinterpret_cast<const bf16x8*>(
                        Lp + (2 + hl) * 16384 + row * 128 + 16 * ((ks * 4 + fg) ^ (fr & 7)));
                }
        asm volatile("s_waitcnt lgkmcnt(0)" ::: "memory");
        __builtin_amdgcn_sched_barrier(0);
        __builtin_amdgcn_s_barrier();     // all waves done READING buf[par]
        __builtin_amdgcn_sched_barrier(0);
        if (it + 2 < NCHUNK) stage(it + 2, par);   // refill buf[par]
        __builtin_amdgcn_sched_barrier(0);

        __builtin_amdgcn_s_setprio(1);
#pragma unroll
        for (int ks = 0; ks < 2; ++ks)
#pragma unroll
            for (int mf = 0; mf < 4; ++mf)
#pragma unroll
                for (int nf = 0; nf < 2; ++nf) {
                    acc[mf][nf] = __builtin_amdgcn_mfma_f32_16x16x32_bf16(
                        a[0][ks][mf], b[0][ks][nf], acc[mf][nf], 0, 0, 0);   // hi.hi
                    acc[mf][nf] = __builtin_amdgcn_mfma_f32_16x16x32_bf16(
                        a[0][ks][mf], b[1][ks][nf], acc[mf][nf], 0, 0, 0);   // hi.lo
                    acc[mf][nf] = __builtin_amdgcn_mfma_f32_16x16x32_bf16(
                        a[1][ks][mf], b[0][ks][nf], acc[mf][nf], 0, 0, 0);   // lo.hi
                }
        __builtin_amdgcn_s_setprio(0);
    }
}

// ---------------------------------------------------------------------------
// MFMA GEMM core v6 — BK=32 with hi|lo COLUMN-INTERLEAVE, 64 KB LDS.
// Combined tiles: [128][64] bf16 where cols 0..31 = hi k-chunk, 32..63 = lo.
// Rows stay 128 B -> proven 8-slot XOR swizzle & bank structure unchanged;
// the per-lane GLOBAL source picks hi vs lo by logical slot (legal: only the
// LDS dest is wave-uniform). 4 gll16/stage -> steady vmcnt(4).
// 512 thr, 8 waves (2m x 4n), tile 128x128. Same 3 products per k=32.
// ---------------------------------------------------------------------------
template<int NCHUNK, int SEG>
__device__ __forceinline__ void gemm_core32(
    const unsigned short* __restrict__ Abase, long long Astride,
    const unsigned short* __restrict__ Bbase, long long Bstride,
    int k0, f32x4 (&acc)[4][2], unsigned short* L)   // L: 2*2*128*64 elems = 64 KB
{
    const int t = threadIdx.x;
    const int w = t >> 6, lane = t & 63;
    const int rl8 = lane >> 3, slot = lane & 7;
    const int wm = w >> 2, wn = w & 3;
    const int fr = lane & 15, fg = lane >> 4;
    const int g    = slot ^ rl8;                           // logical k-group at this slot
    const int goff = (g < 4) ? g * 8 : SEG + (g - 4) * 8;  // hi cols 0..3, lo cols 4..7

    long long arow[2], brow[2];
    int ci[2];
#pragma unroll
    for (int c = 0; c < 2; ++c) {
        ci[c] = w * 2 + c;                   // 16 ci x 8 rl8 = 128 rows
        const int row = ci[c] * 8 + rl8;
        arow[c] = (long long)row * Astride;
        brow[c] = (long long)row * Bstride;
    }

    auto stage = [&](int chunk, int par) {
        const int kin = k0 + chunk * 32;
        char* Lp = (char*)L + par * 32768;
#pragma unroll
        for (int c = 0; c < 2; ++c) {
            gll16(Abase + arow[c] + goff + kin, Lp + 0 * 16384 + ci[c] * 1024); // A hi|lo
            gll16(Bbase + brow[c] + goff + kin, Lp + 1 * 16384 + ci[c] * 1024); // B hi|lo
        }
    };

    stage(0, 0);
    stage(1, 1);                          // 8 loads in flight

    for (int it = 0; it < NCHUNK; ++it) {
        const int par = it & 1;
        if (it + 1 < NCHUNK) asm volatile("s_waitcnt vmcnt(4)" ::: "memory");
        else                 asm volatile("s_waitcnt vmcnt(0)" ::: "memory");
        __builtin_amdgcn_s_barrier();     // buf[par] ready for every wave

        const char* Lp = (const char*)L + par * 32768;
        bf16x8 a[2][4], b[2][2];          // [hl][frag]
#pragma unroll
        for (int hl = 0; hl < 2; ++hl)
#pragma unroll
            for (int mf = 0; mf < 4; ++mf) {
                const int row = wm * 64 + mf * 16 + fr;
                a[hl][mf] = *reinterpret_cast<const bf16x8*>(
                    Lp + row * 128 + 16 * ((hl * 4 + fg) ^ (fr & 7)));
            }
#pragma unroll
        for (int hl = 0; hl < 2; ++hl)
#pragma unroll
            for (int nf = 0; nf < 2; ++nf) {
                const int row = wn * 32 + nf * 16 + fr;
                b[hl][nf] = *reinterpret_cast<const bf16x8*>(
                    Lp + 16384 + row * 128 + 16 * ((hl * 4 + fg) ^ (fr & 7)));
            }
        asm volatile("s_waitcnt lgkmcnt(0)" ::: "memory");
        __builtin_amdgcn_sched_barrier(0);
        __builtin_amdgcn_s_barrier();     // all waves done READING buf[par]
        __builtin_amdgcn_sched_barrier(0);
        if (it + 2 < NCHUNK) stage(it + 2, par);   // refill buf[par]
        __builtin_amdgcn_sched_barrier(0);

        __builtin_amdgcn_s_setprio(1);
#pragma unroll
        for (int mf = 0; mf < 4; ++mf)
#pragma unroll
            for (int nf = 0; nf < 2; ++nf) {
                acc[mf][nf] = __builtin_amdgcn_mfma_f32_16x16x32_bf16(
                    a[0][mf], b[0][nf], acc[mf][nf], 0, 0, 0);   // hi.hi
                acc[mf][nf] = __builtin_amdgcn_mfma_f32_16x16x32_bf16(
                    a[0][mf], b[1][nf], acc[mf][nf], 0, 0, 0);   // hi.lo
                acc[mf][nf] = __builtin_amdgcn_mfma_f32_16x16x32_bf16(
                    a[1][mf], b[0][nf], acc[mf][nf], 0, 0, 0);   // lo.hi
            }
        __builtin_amdgcn_s_setprio(0);
    }
}

// ---------------------------------------------------------------------------
// prep1: fusew's prerequisites only (round-12 prep1, proven). blockIdx-ranged:
//   [0, 7680)      w1tc: w1 f32 [j][q] -> w1T2 bf16 hi|lo [q][jcat]
//   [7680, 7936)   w2prep + bfused
// ---------------------------------------------------------------------------
__global__ __launch_bounds__(256) void prep1_kernel(
    const float* __restrict__ w1, const float* __restrict__ w2,
    const float* __restrict__ b1, const float* __restrict__ b2,
    unsigned short* __restrict__ w1T2, unsigned short* __restrict__ w2cat,
    float* __restrict__ bf) {
    __shared__ __align__(16) char smem[16640];
    const int blk = blockIdx.x;
    const int t = threadIdx.x;

    if (blk < NB_W1T) {
        float (*L)[65] = (float (*)[65])smem;
        const int q0 = (blk % (DIN / 64)) * 64, j0 = (blk / (DIN / 64)) * 64;
        const int tr = t >> 4, tc4 = (t & 15) * 4;
#pragma unroll
        for (int jj = 0; jj < 4; ++jj) {
            const int j = jj * 16 + tr;
            const float4 v = *(const float4*)(w1 + (size_t)(j0 + j) * DIN + q0 + tc4);
            L[j][tc4] = v.x; L[j][tc4 + 1] = v.y; L[j][tc4 + 2] = v.z; L[j][tc4 + 3] = v.w;
        }
        __syncthreads();
#pragma unroll
        for (int pass = 0; pass < 4; ++pass) {
            const int ql = pass * 16 + tr;
            const int jc = tc4;
            ushort4 h4, l4;
            float v0 = L[jc + 0][ql], v1 = L[jc + 1][ql], v2 = L[jc + 2][ql], v3 = L[jc + 3][ql];
            h4.x = f2bf(v0); l4.x = f2bf(v0 - bf2f(h4.x));
            h4.y = f2bf(v1); l4.y = f2bf(v1 - bf2f(h4.y));
            h4.z = f2bf(v2); l4.z = f2bf(v2 - bf2f(h4.z));
            h4.w = f2bf(v3); l4.w = f2bf(v3 - bf2f(h4.w));
            *(ushort4*)(w1T2 + (size_t)(q0 + ql) * 2048 + j0 + jc)        = h4;
            *(ushort4*)(w1T2 + (size_t)(q0 + ql) * 2048 + 1024 + j0 + jc) = l4;
        }
    } else {
        float* red = (float*)smem;
        const int p = blk - NB_W1T;
        float acc = 0.f;
#pragma unroll
        for (int j = t; j < N1_; j += 256) {
            const float v = w2[(size_t)p * N1_ + j];
            const unsigned short hi = f2bf(v);
            const unsigned short lo = f2bf(v - bf2f(hi));
            w2cat[(size_t)p * 2048 + j]        = hi;
            w2cat[(size_t)p * 2048 + 1024 + j] = lo;
            acc = fmaf(v, b1[j], acc);
        }
        red[t] = acc; __syncthreads();
        for (int s = 128; s > 0; s >>= 1) { if (t < s) red[t] += red[t + s]; __syncthreads(); }
        if (t == 0) bf[p] = red[0] + b2[p];
    }
}

// ---------------------------------------------------------------------------
// mega2: fusew (compute-bound, BK=32 core, 64 KB) + roi (BW-bound, 38.4 KB)
// in ONE launch with 64 KB LDS union -> 2 blocks/CU (fixes round-12's
// 1-block/CU starvation). roi's HBM streaming hides under fusew's MFMA.
//   [0, 480)       fusew tile (pb,qb), XCD remap 8 x 60
//   [480, 4320)    roi: CPB=2 channels staged in LDS, 512 threads
// ---------------------------------------------------------------------------
__global__ __launch_bounds__(512, 4) void mega2_kernel(
    const float* __restrict__ z, const float* __restrict__ bboxs,
    const unsigned short* __restrict__ w2cat, const unsigned short* __restrict__ w1T2,
    unsigned short* __restrict__ W2, unsigned short* __restrict__ flat2) {
    __shared__ __align__(16) char smem[65536];
    const int blk = blockIdx.x;
    const int t = threadIdx.x;

    if (blk < NB_FW) {
        // ----- fusew: Wout[p][q] = sum_j w2[p][j] w1[j][q], BK=32 core -----
        unsigned short* L = (unsigned short*)smem;
        const int xcd = blk & 7, j = blk >> 3;     // j 0..59
        const int pb = j & 1;
        const int qb = xcd * 30 + (j >> 1);        // 0..239
        f32x4 acc[4][2];
#pragma unroll
        for (int i = 0; i < 4; ++i)
#pragma unroll
            for (int k = 0; k < 2; ++k) acc[i][k] = (f32x4){0.f, 0.f, 0.f, 0.f};

        gemm_core32<NCH_FW, N1_>(w2cat + (long long)pb * 128 * 2048, 2048,
                                 w1T2 + (long long)qb * 128 * 2048, 2048,
                                 0, acc, L);

        const int w = t >> 6, lane = t & 63;
        const int wm = w >> 2, wn = w & 3;
        const int fr = lane & 15, fg = lane >> 4;
#pragma unroll
        for (int mf = 0; mf < 4; ++mf)
#pragma unroll
            for (int nf = 0; nf < 2; ++nf)
#pragma unroll
                for (int r = 0; r < 4; ++r) {
                    const int p = pb * 128 + wm * 64 + mf * 16 + fg * 4 + r;
                    const int q = qb * 128 + wn * 32 + nf * 16 + fr;
                    const float v = acc[mf][nf][r];
                    const unsigned short hi = f2bf(v);
                    const unsigned short lo = f2bf(v - bf2f(hi));
                    W2[(size_t)p * (2 * DIN) + q]       = hi;
                    W2[(size_t)p * (2 * DIN) + DIN + q] = lo;
                }
    } else {
        // ----- roi: 2 channels staged in LDS, 512 threads -----
        float* img = (float*)smem;                       // 2*4800 floats = 38400 B
        float (*bxc)[4] = (float (*)[4])(smem + 38400);  // 64*4 floats
        const int idx = blk - NB_FW;
        const int b  = idx / (C_ / CPB);
        const int cg = idx % (C_ / CPB);
        const float* zb = z + ((size_t)b * C_ + (size_t)cg * CPB) * (size_t)(T_ * IMG)
                            + (size_t)(T_ - 1) * IMG;
#pragma unroll
        for (int c = 0; c < CPB; ++c) {
            const float4* src = (const float4*)(zb + (size_t)c * (T_ * IMG));
            float4* dst = (float4*)(img + c * IMG);
            for (int i = t; i < IMG / 4; i += 512) dst[i] = src[i];
        }
        if (t < 64) {
            const float* bp = bboxs + ((size_t)b * 64 + t) * 4;
            const float v0 = bp[0], v1 = bp[1], v2 = bp[2], v3 = bp[3];
            bxc[t][0] = isnan(v0) ? 0.f : v0;
            bxc[t][1] = isnan(v1) ? 0.f : v1;
            bxc[t][2] = isnan(v2) ? 0.f : v2;
            bxc[t][3] = isnan(v3) ? 0.f : v3;
        }
        __syncthreads();

        const int p = t & 63, mh = t >> 6;               // mh 0..7
        const int gy = p >> 3, gx = p & 7;
        for (int mq = 0; mq < 8; ++mq) {
            const int m = mq * 8 + mh;
            const float x1 = bxc[m][0] * 0.125f - 0.5f;
            const float y1 = bxc[m][1] * 0.125f - 0.5f;
            const float x2 = bxc[m][2] * 0.125f - 0.5f;
            const float y2 = bxc[m][3] * 0.125f - 0.5f;
            const float bw = (x2 - x1) * (1.0f / OS_);
            const float bh = (y2 - y1) * (1.0f / OS_);
            const float X = x1 + ((float)gx + 0.5f) * bw;
            const float Y = y1 + ((float)gy + 0.5f) * bh;
            const bool valid = (Y >= -1.0f) && (Y <= (float)FY_) &&
                               (X >= -1.0f) && (X <= (float)FX_);
            const float yc = fminf(fmaxf(Y, 0.f), (float)(FY_ - 1));
            const float xc = fminf(fmaxf(X, 0.f), (float)(FX_ - 1));
            const float y0f = floorf(yc), x0f = floorf(xc);
            const int y0 = (int)y0f, x0 = (int)x0f;
            const int y1i = min(y0 + 1, FY_ - 1);
            const int x1i = min(x0 + 1, FX_ - 1);
            const float ly = yc - y0f, lx = xc - x0f;
            const float hy = 1.f - ly,  hx = 1.f - lx;
            float w00 = hy * hx, w01 = hy * lx, w10 = ly * hx, w11 = ly * lx;
            if (!valid) { w00 = 0.f; w01 = 0.f; w10 = 0.f; w11 = 0.f; }
            const int i00 = y0 * FX_ + x0, i01 = y0 * FX_ + x1i;
            const int i10 = y1i * FX_ + x0, i11 = y1i * FX_ + x1i;
            unsigned short* fo = flat2 + (size_t)(b * 64 + m) * (2 * DIN)
                                       + cg * (CPB * 64) + p;
#pragma unroll
            for (int c = 0; c < CPB; ++c) {
                const float* f = img + c * IMG;
                const float v = w00 * f[i00] + w01 * f[i01] + w10 * f[i10] + w11 * f[i11];
                const unsigned short hi = f2bf(v);
                const unsigned short lo = f2bf(v - bf2f(hi));
                fo[c * 64]       = hi;
                fo[DIN + c * 64] = lo;
            }
        }
    }
}

// ---------------------------------------------------------------------------
// zz partials (round-13 verbatim): part[sp][m][n]. 128x128 tile, 512 thr,
// v5 core (BK=64), K split 16. grid 256 = 1 block/CU, single round.
// XCD remap bijective (256 = 8 x 32).
// ---------------------------------------------------------------------------
__global__ __launch_bounds__(512, 1) void zz_mfma(const unsigned short* __restrict__ flat2,
                                                  const unsigned short* __restrict__ W2,
                                                  float* __restrict__ part) {
    __shared__ __align__(16) unsigned short L[2 * 4 * 128 * 64];   // 128 KB
    const int bid = blockIdx.x;
    const int xcd = bid & 7, j = bid >> 3;     // j 0..31
    const int mb = j & 7;
    const int pair = xcd * 4 + (j >> 3);       // 0..31
    const int nb = pair & 1, sp = pair >> 1;   // nb 0..1, sp 0..15
    f32x4 acc[4][2];
#pragma unroll
    for (int i = 0; i < 4; ++i)
#pragma unroll
        for (int k = 0; k < 2; ++k) acc[i][k] = (f32x4){0.f, 0.f, 0.f, 0.f};

    gemm_core<NCH_ZZ, DIN>(flat2 + (long long)mb * 128 * (2 * DIN), 2 * DIN,
                           W2 + (long long)nb * 128 * (2 * DIN), 2 * DIN,
                           sp * (NCH_ZZ * 64), acc, L);

    float* po = part + (size_t)sp * (M_ * N2_);
    const int t = threadIdx.x;
    const int w = t >> 6, lane = t & 63;
    const int wm = w >> 2, wn = w & 3;
    const int fr = lane & 15, fg = lane >> 4;
#pragma unroll
    for (int mf = 0; mf < 4; ++mf)
#pragma unroll
        for (int nf = 0; nf < 2; ++nf)
#pragma unroll
            for (int r = 0; r < 4; ++r) {
                const int m = mb * 128 + wm * 64 + mf * 16 + fg * 4 + r;
                const int n = nb * 128 + wn * 32 + nf * 16 + fr;
                po[(size_t)m * N2_ + n] = acc[mf][nf][r];
            }
}

// ---------------------------------------------------------------------------
// Fused reduce + cluster: one block per sample m, 256 threads (t = n).
// ---------------------------------------------------------------------------
__global__ __launch_bounds__(256) void reduce_cluster_kernel(
    const float* __restrict__ part, const float* __restrict__ bf,
    const float* __restrict__ cent,
    float* __restrict__ out_zz, float* __restrict__ out_s, float* __restrict__ out_c) {
    __shared__ float row[N2_];
    const int m = blockIdx.x, t = threadIdx.x;
    float a = bf[t];
#pragma unroll
    for (int s = 0; s < SPLITK; ++s) a += part[(size_t)s * (M_ * N2_) + (size_t)m * N2_ + t];
    out_zz[(size_t)m * N2_ + t] = a;
    row[t] = a;
    __syncthreads();
    if (t < 64) {
        const float* cr = cent + (size_t)t * N2_;
        float dot = 0.f, c2 = 0.f, z2 = 0.f;
        for (int d = 0; d < N2_; ++d) {
            const float zv = row[d], cv = cr[d];
            dot = fmaf(zv, cv, dot);
            c2  = fmaf(cv, cv, c2);
            z2  = fmaf(zv, zv, z2);
        }
        const float nrm = sqrtf(fmaxf(z2 + c2 - 2.f * dot, 0.f));
        const float su = 1.0f / (1.0f + nrm);
        float ssum = su;
#pragma unroll
        for (int mk = 1; mk < 64; mk <<= 1) ssum += __shfl_xor(ssum, mk, 64);
        const float s = su / ssum;
        out_s[(size_t)m * 64 + t] = s;
        float bv = s; int bi = t;
#pragma unroll
        for (int mk = 1; mk < 64; mk <<= 1) {
            const float ov = __shfl_xor(bv, mk, 64);
            const int   oi = __shfl_xor(bi, mk, 64);
            if (ov > bv || (ov == bv && oi < bi)) { bv = ov; bi = oi; }
        }
        if (t == 0) out_c[m] = (float)bi;
    }
}

// ---------------------------------------------------------------------------
extern "C" void kernel_launch(void* const* d_in, const int* in_sizes, int n_in,
                              void* d_out, int out_size, void* d_ws, size_t ws_size,
                              hipStream_t stream) {
    const float* z     = (const float*)d_in[0];
    const float* bboxs = (const float*)d_in[1];
    const float* w1    = (const float*)d_in[2];
    const float* b1    = (const float*)d_in[3];
    const float* w2    = (const float*)d_in[4];
    const float* b2    = (const float*)d_in[5];
    const float* cent  = (const float*)d_in[6];
    float* out = (float*)d_out;
    float* out_zz = out;                                        // 1024*256
    float* out_s  = out + (size_t)M_ * N2_;                     // 1024*64
    float* out_c  = out + (size_t)M_ * N2_ + (size_t)M_ * K_;   // 1024

    char* ws = (char*)d_ws;                                     // ws >= 1.1 GB
    unsigned short* w1T2   = (unsigned short*)(ws);                  // 125,829,120 B
    unsigned short* flat2  = (unsigned short*)(ws + 125829120u);     // 125,829,120 B
    unsigned short* W2     = (unsigned short*)(ws + 251658240u);     //  31,457,280 B
    float*          part   = (float*)(ws + 283115520u);              //  16,777,216 B
    unsigned short* w2cat  = (unsigned short*)(ws + 316669952u);     //   1,048,576 B
    float*          bfused = (float*)(ws + 317718528u);              //       1,024 B

    prep1_kernel<<<dim3(NB_W1T + NB_W2P), dim3(256), 0, stream>>>(
        w1, w2, b1, b2, w1T2, w2cat, bfused);
    mega2_kernel<<<dim3(NB_FW + NB_ROI), dim3(512), 0, stream>>>(
        z, bboxs, w2cat, w1T2, W2, flat2);
    zz_mfma<<<dim3(256), dim3(512), 0, stream>>>(flat2, W2, part);
    reduce_cluster_kernel<<<dim3(1024), dim3(256), 0, stream>>>(part, bfused, cent,
                                                                out_zz, out_s, out_c);
}

// Round 15
// 226.721 us; speedup vs baseline: 1.1684x; 1.0073x over previous
//
#include <hip/hip_runtime.h>
#include <hip/hip_bf16.h>

// Problem dims (fixed by reference)
static constexpr int B_  = 16;
static constexpr int SN_ = 64;
static constexpr int C_  = 480;
static constexpr int T_  = 2;
static constexpr int FY_ = 60;
static constexpr int FX_ = 80;
static constexpr int OS_ = 8;
static constexpr int DIN = 30720;            // C*OS*OS
static constexpr int M_  = 1024;             // B*SN
static constexpr int N1_ = 1024;
static constexpr int N2_ = 256;
static constexpr int K_  = 64;               // clusters
static constexpr int SPLITK = 16;
static constexpr int NCH_ZZ = (DIN / 64) / SPLITK;  // 30 chunks per split (BK=64 core)
static constexpr int NCH_FW = N1_ / 32;             // 32 chunks (BK=32 core)
static constexpr int CPB = 2;                    // roi channels per block
static constexpr int IMG = FY_ * FX_;            // 4800
// prep mega-kernel block ranges (256 thr)
static constexpr int NB_ROI = 16 * (C_ / CPB);   // 3840
static constexpr int NB_W1T = (DIN / 64) * (N1_ / 64);  // 7680
static constexpr int NB_W2P = N2_;               // 256

typedef __bf16 bf16x8 __attribute__((ext_vector_type(8)));
typedef float  f32x4  __attribute__((ext_vector_type(4)));
typedef unsigned int u32_as1 __attribute__((address_space(1)));
typedef unsigned int u32_as3 __attribute__((address_space(3)));

__device__ __forceinline__ float bf2f(unsigned short u) {
    union { unsigned int i; float f; } v; v.i = ((unsigned int)u) << 16; return v.f;
}
// RNE f32 -> bf16 bits (inputs finite here)
__device__ __forceinline__ unsigned short f2bf(float f) {
    unsigned int u = __float_as_uint(f);
    u = u + 0x7FFFu + ((u >> 16) & 1u);
    return (unsigned short)(u >> 16);
}
__device__ __forceinline__ void gll16(const void* g, void* l) {
    __builtin_amdgcn_global_load_lds((const u32_as1*)g, (u32_as3*)l, 16, 0, 0);
}

// ---------------------------------------------------------------------------
// MFMA GEMM core v5 (BK=64, 128 KB LDS) — used by zz. 4-stage/3-product
// chunking + depth-2 counted vmcnt. 512 thr, 8 waves (2m x 4n), tile 128x128.
// vmcnt(8) waits current buffer only; WAR guarded by lgkm(0)+SB+barrier.
// ---------------------------------------------------------------------------
template<int NCHUNK, int SEG>
__device__ __forceinline__ void gemm_core(
    const unsigned short* __restrict__ Abase, long long Astride,
    const unsigned short* __restrict__ Bbase, long long Bstride,
    int k0, f32x4 (&acc)[4][2], unsigned short* L)   // L: 2*4*128*64 elems
{
    const int t = threadIdx.x;
    const int w = t >> 6, lane = t & 63;
    const int rl8 = lane >> 3, slot = lane & 7;
    const int wm = w >> 2, wn = w & 3;
    const int fr = lane & 15, fg = lane >> 4;
    const int swz8 = (slot ^ rl8) * 8;       // row&7 == rl8 for staging rows

    long long arow[2], brow[2];
    int ci[2];
#pragma unroll
    for (int c = 0; c < 2; ++c) {
        ci[c] = w * 2 + c;                   // 16 ci x 8 rl8 = 128 rows
        const int row = ci[c] * 8 + rl8;
        arow[c] = (long long)row * Astride;
        brow[c] = (long long)row * Bstride;
    }

    auto stage = [&](int chunk, int par) {
        const int kin = k0 + chunk * 64;
        char* Lp = (char*)L + par * 65536;
#pragma unroll
        for (int c = 0; c < 2; ++c) {
            gll16(Abase + arow[c] + kin + swz8,       Lp + 0 * 16384 + ci[c] * 1024); // Ahi
            gll16(Abase + arow[c] + SEG + kin + swz8, Lp + 1 * 16384 + ci[c] * 1024); // Alo
            gll16(Bbase + brow[c] + kin + swz8,       Lp + 2 * 16384 + ci[c] * 1024); // Bhi
            gll16(Bbase + brow[c] + SEG + kin + swz8, Lp + 3 * 16384 + ci[c] * 1024); // Blo
        }
    };

    stage(0, 0);
    stage(1, 1);                          // 16 loads in flight

    for (int it = 0; it < NCHUNK; ++it) {
        const int par = it & 1;
        if (it + 1 < NCHUNK) asm volatile("s_waitcnt vmcnt(8)" ::: "memory");
        else                 asm volatile("s_waitcnt vmcnt(0)" ::: "memory");
        __builtin_amdgcn_s_barrier();     // buf[par] ready for every wave

        const char* Lp = (const char*)L + par * 65536;
        bf16x8 a[2][2][4], b[2][2][2];    // [hl][ks][frag]
#pragma unroll
        for (int hl = 0; hl < 2; ++hl)
#pragma unroll
            for (int ks = 0; ks < 2; ++ks)
#pragma unroll
                for (int mf = 0; mf < 4; ++mf) {
                    const int row = wm * 64 + mf * 16 + fr;
                    a[hl][ks][mf] = *reinterpret_cast<const bf16x8*>(
                        Lp + hl * 16384 + row * 128 + 16 * ((ks * 4 + fg) ^ (fr & 7)));
                }
#pragma unroll
        for (int hl = 0; hl < 2; ++hl)
#pragma unroll
            for (int ks = 0; ks < 2; ++ks)
#pragma unroll
                for (int nf = 0; nf < 2; ++nf) {
                    const int row = wn * 32 + nf * 16 + fr;
                    b[hl][ks][nf] = *reinterpret_cast<const bf16x8*>(
                        Lp + (2 + hl) * 16384 + row * 128 + 16 * ((ks * 4 + fg) ^ (fr & 7)));
                }
        asm volatile("s_waitcnt lgkmcnt(0)" ::: "memory");
        __builtin_amdgcn_sched_barrier(0);
        __builtin_amdgcn_s_barrier();     // all waves done READING buf[par]
        __builtin_amdgcn_sched_barrier(0);
        if (it + 2 < NCHUNK) stage(it + 2, par);   // refill buf[par]
        __builtin_amdgcn_sched_barrier(0);

        __builtin_amdgcn_s_setprio(1);
#pragma unroll
        for (int ks = 0; ks < 2; ++ks)
#pragma unroll
            for (int mf = 0; mf < 4; ++mf)
#pragma unroll
                for (int nf = 0; nf < 2; ++nf) {
                    acc[mf][nf] = __builtin_amdgcn_mfma_f32_16x16x32_bf16(
                        a[0][ks][mf], b[0][ks][nf], acc[mf][nf], 0, 0, 0);   // hi.hi
                    acc[mf][nf] = __builtin_amdgcn_mfma_f32_16x16x32_bf16(
                        a[0][ks][mf], b[1][ks][nf], acc[mf][nf], 0, 0, 0);   // hi.lo
                    acc[mf][nf] = __builtin_amdgcn_mfma_f32_16x16x32_bf16(
                        a[1][ks][mf], b[0][ks][nf], acc[mf][nf], 0, 0, 0);   // lo.hi
                }
        __builtin_amdgcn_s_setprio(0);
    }
}

// ---------------------------------------------------------------------------
// MFMA GEMM core v6 (round-14 verified) — BK=32, hi|lo column-interleave,
// 64 KB LDS -> fusew runs 2 blocks/CU (cross-block wave overlap covers
// staging stalls). Per-lane GLOBAL source picks hi/lo by logical slot;
// LDS dest stays linear (m104 rule). 4 gll16/stage -> steady vmcnt(4).
// ---------------------------------------------------------------------------
template<int NCHUNK, int SEG>
__device__ __forceinline__ void gemm_core32(
    const unsigned short* __restrict__ Abase, long long Astride,
    const unsigned short* __restrict__ Bbase, long long Bstride,
    int k0, f32x4 (&acc)[4][2], unsigned short* L)   // L: 2*2*128*64 elems = 64 KB
{
    const int t = threadIdx.x;
    const int w = t >> 6, lane = t & 63;
    const int rl8 = lane >> 3, slot = lane & 7;
    const int wm = w >> 2, wn = w & 3;
    const int fr = lane & 15, fg = lane >> 4;
    const int g    = slot ^ rl8;                           // logical k-group at this slot
    const int goff = (g < 4) ? g * 8 : SEG + (g - 4) * 8;  // hi cols 0..3, lo cols 4..7

    long long arow[2], brow[2];
    int ci[2];
#pragma unroll
    for (int c = 0; c < 2; ++c) {
        ci[c] = w * 2 + c;                   // 16 ci x 8 rl8 = 128 rows
        const int row = ci[c] * 8 + rl8;
        arow[c] = (long long)row * Astride;
        brow[c] = (long long)row * Bstride;
    }

    auto stage = [&](int chunk, int par) {
        const int kin = k0 + chunk * 32;
        char* Lp = (char*)L + par * 32768;
#pragma unroll
        for (int c = 0; c < 2; ++c) {
            gll16(Abase + arow[c] + goff + kin, Lp + 0 * 16384 + ci[c] * 1024); // A hi|lo
            gll16(Bbase + brow[c] + goff + kin, Lp + 1 * 16384 + ci[c] * 1024); // B hi|lo
        }
    };

    stage(0, 0);
    stage(1, 1);                          // 8 loads in flight

    for (int it = 0; it < NCHUNK; ++it) {
        const int par = it & 1;
        if (it + 1 < NCHUNK) asm volatile("s_waitcnt vmcnt(4)" ::: "memory");
        else                 asm volatile("s_waitcnt vmcnt(0)" ::: "memory");
        __builtin_amdgcn_s_barrier();     // buf[par] ready for every wave

        const char* Lp = (const char*)L + par * 32768;
        bf16x8 a[2][4], b[2][2];          // [hl][frag]
#pragma unroll
        for (int hl = 0; hl < 2; ++hl)
#pragma unroll
            for (int mf = 0; mf < 4; ++mf) {
                const int row = wm * 64 + mf * 16 + fr;
                a[hl][mf] = *reinterpret_cast<const bf16x8*>(
                    Lp + row * 128 + 16 * ((hl * 4 + fg) ^ (fr & 7)));
            }
#pragma unroll
        for (int hl = 0; hl < 2; ++hl)
#pragma unroll
            for (int nf = 0; nf < 2; ++nf) {
                const int row = wn * 32 + nf * 16 + fr;
                b[hl][nf] = *reinterpret_cast<const bf16x8*>(
                    Lp + 16384 + row * 128 + 16 * ((hl * 4 + fg) ^ (fr & 7)));
            }
        asm volatile("s_waitcnt lgkmcnt(0)" ::: "memory");
        __builtin_amdgcn_sched_barrier(0);
        __builtin_amdgcn_s_barrier();     // all waves done READING buf[par]
        __builtin_amdgcn_sched_barrier(0);
        if (it + 2 < NCHUNK) stage(it + 2, par);   // refill buf[par]
        __builtin_amdgcn_sched_barrier(0);

        __builtin_amdgcn_s_setprio(1);
#pragma unroll
        for (int mf = 0; mf < 4; ++mf)
#pragma unroll
            for (int nf = 0; nf < 2; ++nf) {
                acc[mf][nf] = __builtin_amdgcn_mfma_f32_16x16x32_bf16(
                    a[0][mf], b[0][nf], acc[mf][nf], 0, 0, 0);   // hi.hi
                acc[mf][nf] = __builtin_amdgcn_mfma_f32_16x16x32_bf16(
                    a[0][mf], b[1][nf], acc[mf][nf], 0, 0, 0);   // hi.lo
                acc[mf][nf] = __builtin_amdgcn_mfma_f32_16x16x32_bf16(
                    a[1][mf], b[0][nf], acc[mf][nf], 0, 0, 0);   // lo.hi
            }
        __builtin_amdgcn_s_setprio(0);
    }
}

// ---------------------------------------------------------------------------
// PREP mega-kernel (round-13 verbatim): blockIdx-ranged dispatch of three
// independent memory-bound preps sharing HBM BW. Union LDS 39,424 B
// -> 4 blocks/CU.
// ---------------------------------------------------------------------------
__global__ __launch_bounds__(256) void prep_kernel(
    const float* __restrict__ z, const float* __restrict__ bboxs,
    const float* __restrict__ w1, const float* __restrict__ w2,
    const float* __restrict__ b1, const float* __restrict__ b2,
    unsigned short* __restrict__ flat2, unsigned short* __restrict__ w1T2,
    unsigned short* __restrict__ w2cat, float* __restrict__ bf) {
    __shared__ __align__(16) char smem[39424];
    const int blk = blockIdx.x;
    const int t = threadIdx.x;

    if (blk < NB_ROI) {
        float* img = (float*)smem;                       // 2*4800 floats
        float (*bxc)[4] = (float (*)[4])(smem + 38400);  // 64*4 floats
        const int b  = blk / (C_ / CPB);
        const int cg = blk % (C_ / CPB);
        const float* zb = z + ((size_t)b * C_ + (size_t)cg * CPB) * (size_t)(T_ * IMG)
                            + (size_t)(T_ - 1) * IMG;
#pragma unroll
        for (int c = 0; c < CPB; ++c) {
            const float4* src = (const float4*)(zb + (size_t)c * (T_ * IMG));
            float4* dst = (float4*)(img + c * IMG);
            for (int i = t; i < IMG / 4; i += 256) dst[i] = src[i];
        }
        if (t < 64) {
            const float* bp = bboxs + ((size_t)b * 64 + t) * 4;
            const float v0 = bp[0], v1 = bp[1], v2 = bp[2], v3 = bp[3];
            bxc[t][0] = isnan(v0) ? 0.f : v0;
            bxc[t][1] = isnan(v1) ? 0.f : v1;
            bxc[t][2] = isnan(v2) ? 0.f : v2;
            bxc[t][3] = isnan(v3) ? 0.f : v3;
        }
        __syncthreads();

        const int p = t & 63, mh = t >> 6;
        const int gy = p >> 3, gx = p & 7;
        for (int mq = 0; mq < 16; ++mq) {
            const int m = mq * 4 + mh;
            const float x1 = bxc[m][0] * 0.125f - 0.5f;
            const float y1 = bxc[m][1] * 0.125f - 0.5f;
            const float x2 = bxc[m][2] * 0.125f - 0.5f;
            const float y2 = bxc[m][3] * 0.125f - 0.5f;
            const float bw = (x2 - x1) * (1.0f / OS_);
            const float bh = (y2 - y1) * (1.0f / OS_);
            const float X = x1 + ((float)gx + 0.5f) * bw;
            const float Y = y1 + ((float)gy + 0.5f) * bh;
            const bool valid = (Y >= -1.0f) && (Y <= (float)FY_) &&
                               (X >= -1.0f) && (X <= (float)FX_);
            const float yc = fminf(fmaxf(Y, 0.f), (float)(FY_ - 1));
            const float xc = fminf(fmaxf(X, 0.f), (float)(FX_ - 1));
            const float y0f = floorf(yc), x0f = floorf(xc);
            const int y0 = (int)y0f, x0 = (int)x0f;
            const int y1i = min(y0 + 1, FY_ - 1);
            const int x1i = min(x0 + 1, FX_ - 1);
            const float ly = yc - y0f, lx = xc - x0f;
            const float hy = 1.f - ly,  hx = 1.f - lx;
            float w00 = hy * hx, w01 = hy * lx, w10 = ly * hx, w11 = ly * lx;
            if (!valid) { w00 = 0.f; w01 = 0.f; w10 = 0.f; w11 = 0.f; }
            const int i00 = y0 * FX_ + x0, i01 = y0 * FX_ + x1i;
            const int i10 = y1i * FX_ + x0, i11 = y1i * FX_ + x1i;
            unsigned short* fo = flat2 + (size_t)(b * 64 + m) * (2 * DIN)
                                       + cg * (CPB * 64) + p;
#pragma unroll
            for (int c = 0; c < CPB; ++c) {
                const float* f = img + c * IMG;
                const float v = w00 * f[i00] + w01 * f[i01] + w10 * f[i10] + w11 * f[i11];
                const unsigned short hi = f2bf(v);
                const unsigned short lo = f2bf(v - bf2f(hi));
                fo[c * 64]       = hi;
                fo[DIN + c * 64] = lo;
            }
        }
    } else if (blk < NB_ROI + NB_W1T) {
        float (*L)[65] = (float (*)[65])smem;
        const int idx = blk - NB_ROI;
        const int q0 = (idx % (DIN / 64)) * 64, j0 = (idx / (DIN / 64)) * 64;
        const int tr = t >> 4, tc4 = (t & 15) * 4;
#pragma unroll
        for (int jj = 0; jj < 4; ++jj) {
            const int j = jj * 16 + tr;
            const float4 v = *(const float4*)(w1 + (size_t)(j0 + j) * DIN + q0 + tc4);
            L[j][tc4] = v.x; L[j][tc4 + 1] = v.y; L[j][tc4 + 2] = v.z; L[j][tc4 + 3] = v.w;
        }
        __syncthreads();
#pragma unroll
        for (int pass = 0; pass < 4; ++pass) {
            const int ql = pass * 16 + tr;
            const int jc = tc4;
            ushort4 h4, l4;
            float v0 = L[jc + 0][ql], v1 = L[jc + 1][ql], v2 = L[jc + 2][ql], v3 = L[jc + 3][ql];
            h4.x = f2bf(v0); l4.x = f2bf(v0 - bf2f(h4.x));
            h4.y = f2bf(v1); l4.y = f2bf(v1 - bf2f(h4.y));
            h4.z = f2bf(v2); l4.z = f2bf(v2 - bf2f(h4.z));
            h4.w = f2bf(v3); l4.w = f2bf(v3 - bf2f(h4.w));
            *(ushort4*)(w1T2 + (size_t)(q0 + ql) * 2048 + j0 + jc)        = h4;
            *(ushort4*)(w1T2 + (size_t)(q0 + ql) * 2048 + 1024 + j0 + jc) = l4;
        }
    } else {
        float* red = (float*)smem;
        const int p = blk - (NB_ROI + NB_W1T);
        float acc = 0.f;
#pragma unroll
        for (int j = t; j < N1_; j += 256) {
            const float v = w2[(size_t)p * N1_ + j];
            const unsigned short hi = f2bf(v);
            const unsigned short lo = f2bf(v - bf2f(hi));
            w2cat[(size_t)p * 2048 + j]        = hi;
            w2cat[(size_t)p * 2048 + 1024 + j] = lo;
            acc = fmaf(v, b1[j], acc);
        }
        red[t] = acc; __syncthreads();
        for (int s = 128; s > 0; s >>= 1) { if (t < s) red[t] += red[t + s]; __syncthreads(); }
        if (t == 0) bf[p] = red[0] + b2[p];
    }
}

// ---------------------------------------------------------------------------
// fusew standalone with v6 BK=32 core: 64 KB LDS -> 2 blocks/CU (16 waves/CU
// cross-block overlap). XCD remap 8 x 60 (bijective). grid 480, 512 thr.
// ---------------------------------------------------------------------------
__global__ __launch_bounds__(512, 2) void fusew_mfma(const unsigned short* __restrict__ w2cat,
                                                     const unsigned short* __restrict__ w1T2,
                                                     unsigned short* __restrict__ W2) {
    __shared__ __align__(16) unsigned short L[2 * 2 * 128 * 64];   // 64 KB
    const int bid = blockIdx.x;
    const int xcd = bid & 7, j = bid >> 3;     // j 0..59
    const int pb = j & 1;
    const int qb = xcd * 30 + (j >> 1);        // 0..239
    f32x4 acc[4][2];
#pragma unroll
    for (int i = 0; i < 4; ++i)
#pragma unroll
        for (int k = 0; k < 2; ++k) acc[i][k] = (f32x4){0.f, 0.f, 0.f, 0.f};

    gemm_core32<NCH_FW, N1_>(w2cat + (long long)pb * 128 * 2048, 2048,
                             w1T2 + (long long)qb * 128 * 2048, 2048,
                             0, acc, L);

    const int t = threadIdx.x;
    const int w = t >> 6, lane = t & 63;
    const int wm = w >> 2, wn = w & 3;
    const int fr = lane & 15, fg = lane >> 4;
#pragma unroll
    for (int mf = 0; mf < 4; ++mf)
#pragma unroll
        for (int nf = 0; nf < 2; ++nf)
#pragma unroll
            for (int r = 0; r < 4; ++r) {
                const int p = pb * 128 + wm * 64 + mf * 16 + fg * 4 + r;
                const int q = qb * 128 + wn * 32 + nf * 16 + fr;
                const float v = acc[mf][nf][r];
                const unsigned short hi = f2bf(v);
                const unsigned short lo = f2bf(v - bf2f(hi));
                W2[(size_t)p * (2 * DIN) + q]       = hi;
                W2[(size_t)p * (2 * DIN) + DIN + q] = lo;
            }
}

// ---------------------------------------------------------------------------
// zz partials (round-13 verbatim): part[sp][m][n]. 128x128 tile, 512 thr,
// v5 core (BK=64), K split 16. grid 256 = 1 block/CU, single round.
// XCD remap bijective (256 = 8 x 32).
// ---------------------------------------------------------------------------
__global__ __launch_bounds__(512, 1) void zz_mfma(const unsigned short* __restrict__ flat2,
                                                  const unsigned short* __restrict__ W2,
                                                  float* __restrict__ part) {
    __shared__ __align__(16) unsigned short L[2 * 4 * 128 * 64];   // 128 KB
    const int bid = blockIdx.x;
    const int xcd = bid & 7, j = bid >> 3;     // j 0..31
    const int mb = j & 7;
    const int pair = xcd * 4 + (j >> 3);       // 0..31
    const int nb = pair & 1, sp = pair >> 1;   // nb 0..1, sp 0..15
    f32x4 acc[4][2];
#pragma unroll
    for (int i = 0; i < 4; ++i)
#pragma unroll
        for (int k = 0; k < 2; ++k) acc[i][k] = (f32x4){0.f, 0.f, 0.f, 0.f};

    gemm_core<NCH_ZZ, DIN>(flat2 + (long long)mb * 128 * (2 * DIN), 2 * DIN,
                           W2 + (long long)nb * 128 * (2 * DIN), 2 * DIN,
                           sp * (NCH_ZZ * 64), acc, L);

    float* po = part + (size_t)sp * (M_ * N2_);
    const int t = threadIdx.x;
    const int w = t >> 6, lane = t & 63;
    const int wm = w >> 2, wn = w & 3;
    const int fr = lane & 15, fg = lane >> 4;
#pragma unroll
    for (int mf = 0; mf < 4; ++mf)
#pragma unroll
        for (int nf = 0; nf < 2; ++nf)
#pragma unroll
            for (int r = 0; r < 4; ++r) {
                const int m = mb * 128 + wm * 64 + mf * 16 + fg * 4 + r;
                const int n = nb * 128 + wn * 32 + nf * 16 + fr;
                po[(size_t)m * N2_ + n] = acc[mf][nf][r];
            }
}

// ---------------------------------------------------------------------------
// Fused reduce + cluster: one block per sample m, 256 threads (t = n).
// ---------------------------------------------------------------------------
__global__ __launch_bounds__(256) void reduce_cluster_kernel(
    const float* __restrict__ part, const float* __restrict__ bf,
    const float* __restrict__ cent,
    float* __restrict__ out_zz, float* __restrict__ out_s, float* __restrict__ out_c) {
    __shared__ float row[N2_];
    const int m = blockIdx.x, t = threadIdx.x;
    float a = bf[t];
#pragma unroll
    for (int s = 0; s < SPLITK; ++s) a += part[(size_t)s * (M_ * N2_) + (size_t)m * N2_ + t];
    out_zz[(size_t)m * N2_ + t] = a;
    row[t] = a;
    __syncthreads();
    if (t < 64) {
        const float* cr = cent + (size_t)t * N2_;
        float dot = 0.f, c2 = 0.f, z2 = 0.f;
        for (int d = 0; d < N2_; ++d) {
            const float zv = row[d], cv = cr[d];
            dot = fmaf(zv, cv, dot);
            c2  = fmaf(cv, cv, c2);
            z2  = fmaf(zv, zv, z2);
        }
        const float nrm = sqrtf(fmaxf(z2 + c2 - 2.f * dot, 0.f));
        const float su = 1.0f / (1.0f + nrm);
        float ssum = su;
#pragma unroll
        for (int mk = 1; mk < 64; mk <<= 1) ssum += __shfl_xor(ssum, mk, 64);
        const float s = su / ssum;
        out_s[(size_t)m * 64 + t] = s;
        float bv = s; int bi = t;
#pragma unroll
        for (int mk = 1; mk < 64; mk <<= 1) {
            const float ov = __shfl_xor(bv, mk, 64);
            const int   oi = __shfl_xor(bi, mk, 64);
            if (ov > bv || (ov == bv && oi < bi)) { bv = ov; bi = oi; }
        }
        if (t == 0) out_c[m] = (float)bi;
    }
}

// ---------------------------------------------------------------------------
extern "C" void kernel_launch(void* const* d_in, const int* in_sizes, int n_in,
                              void* d_out, int out_size, void* d_ws, size_t ws_size,
                              hipStream_t stream) {
    const float* z     = (const float*)d_in[0];
    const float* bboxs = (const float*)d_in[1];
    const float* w1    = (const float*)d_in[2];
    const float* b1    = (const float*)d_in[3];
    const float* w2    = (const float*)d_in[4];
    const float* b2    = (const float*)d_in[5];
    const float* cent  = (const float*)d_in[6];
    float* out = (float*)d_out;
    float* out_zz = out;                                        // 1024*256
    float* out_s  = out + (size_t)M_ * N2_;                     // 1024*64
    float* out_c  = out + (size_t)M_ * N2_ + (size_t)M_ * K_;   // 1024

    char* ws = (char*)d_ws;                                     // ws >= 1.1 GB
    unsigned short* w1T2   = (unsigned short*)(ws);                  // 125,829,120 B
    unsigned short* flat2  = (unsigned short*)(ws + 125829120u);     // 125,829,120 B
    unsigned short* W2     = (unsigned short*)(ws + 251658240u);     //  31,457,280 B
    float*          part   = (float*)(ws + 283115520u);              //  16,777,216 B
    unsigned short* w2cat  = (unsigned short*)(ws + 316669952u);     //   1,048,576 B
    float*          bfused = (float*)(ws + 317718528u);              //       1,024 B

    prep_kernel<<<dim3(NB_ROI + NB_W1T + NB_W2P), dim3(256), 0, stream>>>(
        z, bboxs, w1, w2, b1, b2, flat2, w1T2, w2cat, bfused);
    fusew_mfma<<<dim3(480), dim3(512), 0, stream>>>(w2cat, w1T2, W2);
    zz_mfma<<<dim3(256), dim3(512), 0, stream>>>(flat2, W2, part);
    reduce_cluster_kernel<<<dim3(1024), dim3(256), 0, stream>>>(part, bfused, cent,
                                                                out_zz, out_s, out_c);
}